// Round 5
// baseline (169.191 us; speedup 1.0000x reference)
//
#include <hip/hip_runtime.h>
#include <cstddef>
#include <cstdint>

// Problem constants: B=2, T=2048, C=1024, H=16, hs=64
#define B_N 2
#define T_N 2048
#define C_N 1024
#define H_N 16
#define HS_N 64
#define M_N (B_N * T_N)   // 4096

typedef __attribute__((ext_vector_type(8))) short bf16x8;   // 8 bf16 = 4 VGPRs
typedef __attribute__((ext_vector_type(4))) float f32x4;

// 0.125 (hs^-0.5) * log2(e): folded into Wq so attention uses exp2 directly
#define QSCALE 0.18033688011112042f

__device__ __forceinline__ ushort f2bf(float f) {
    union { float f; uint32_t u; } v; v.f = f;
    uint32_t r = v.u + 0x7fffu + ((v.u >> 16) & 1u);   // round-nearest-even
    return (ushort)(r >> 16);
}

// async global->LDS, 16B per lane; lds base must be wave-uniform
#define GLL16(g, l)                                                         \
    __builtin_amdgcn_global_load_lds(                                       \
        (const __attribute__((address_space(1))) unsigned int*)(g),         \
        (__attribute__((address_space(3))) unsigned int*)(l), 16, 0, 0)

// ---------------------------------------------------------------------------
// Fused fp32->bf16 convert: x | Wq(*QSCALE) | Wp | Wk | Wv (one launch).
// ---------------------------------------------------------------------------
__global__ void cvt_all_kernel(const float* __restrict__ x,
                               const float* __restrict__ Wq,
                               const float* __restrict__ Wp,
                               const float* __restrict__ Wk,
                               const float* __restrict__ Wv,
                               ushort* __restrict__ xb,
                               ushort* __restrict__ Wqb,
                               ushort* __restrict__ Wpb,
                               ushort* __restrict__ Wkvb) {
    const int S0 = M_N * C_N / 4;
    const int S1 = S0 + C_N * C_N / 4;
    const int S2 = S1 + C_N * C_N / 4;
    const int S3 = S2 + HS_N * C_N / 4;
    const int S4 = S3 + HS_N * C_N / 4;
    const int stride = gridDim.x * blockDim.x;
    for (int i = blockIdx.x * blockDim.x + threadIdx.x; i < S4; i += stride) {
        const float* src; ushort* dst; int j; float sc = 1.f;
        if (i < S0)      { src = x;  dst = xb;   j = i; }
        else if (i < S1) { src = Wq; dst = Wqb;  j = i - S0; sc = QSCALE; }
        else if (i < S2) { src = Wp; dst = Wpb;  j = i - S1; }
        else if (i < S3) { src = Wk; dst = Wkvb; j = i - S2; }
        else             { src = Wv; dst = Wkvb + HS_N * C_N; j = i - S3; }
        const float4 f = ((const float4*)src)[j];
        ushort4 o;
        o.x = f2bf(f.x * sc); o.y = f2bf(f.y * sc);
        o.z = f2bf(f.z * sc); o.w = f2bf(f.w * sc);
        ((ushort4*)dst)[j] = o;
    }
}

// ---------------------------------------------------------------------------
// bf16 MFMA GEMM, m97-style staging: C[m,n] = sum_k A[m,k]*W[n,k] (+bias[n]).
// BM=128, BN=64, BK=64, 256 threads (4 waves 2x2: 64x32 each).
// Staging via global_load_lds w16 (async, no VGPR round-trip). LDS rows are
// UNPADDED 64-ushort (128B); chunk index XOR-swizzled by (row&7) so both the
// linear lane-order staging writes and the b128 fragment reads spread evenly
// over all 8 bank-groups (balanced 8-phase access = minimum cycles).
// Split output: cols >= Nsplit -> Cout2 (fused q-proj + kv-proj launch).
// ---------------------------------------------------------------------------
template <bool BF16_OUT>
__global__ __launch_bounds__(256) void gemm_bf16_mfma(
    const ushort* __restrict__ A,   // [M][K] bf16
    const ushort* __restrict__ W,   // [Ntot][K] bf16
    const float* __restrict__ bias, // [Nsplit] or nullptr
    void* __restrict__ Cout,        // [M][Nsplit] bf16 or fp32
    ushort* __restrict__ Cout2,     // [M][N2] bf16 or nullptr
    int Nsplit, int N2, int K)
{
    __shared__ ushort As[128 * 64];
    __shared__ ushort Bs[64 * 64];
    const int m0 = blockIdx.x * 128;
    const int n0 = blockIdx.y * 64;
    const int tid = threadIdx.x;
    const int wid = tid >> 6;
    const int lane = tid & 63;
    const int ln = lane & 15;
    const int quad = lane >> 4;
    const int wm = wid >> 1, wn = wid & 1;

    f32x4 acc[4][2];
    #pragma unroll
    for (int i = 0; i < 4; ++i)
        #pragma unroll
        for (int j = 0; j < 2; ++j)
            acc[i][j] = (f32x4){0.f, 0.f, 0.f, 0.f};

    // staging geometry: each 1KB wave-instr covers 8 rows x 8 chunks (16B)
    const int srow = lane >> 3;          // 0..7 row within segment
    const int schk = (lane & 7) ^ srow;  // fetched chunk (row&7 = srow here)

    for (int k0 = 0; k0 < K; k0 += 64) {
        __syncthreads();   // prior iteration's LDS reads complete
        #pragma unroll
        for (int t = 0; t < 4; ++t) {    // A: 16 segments of 8 rows
            const int seg = wid * 4 + t;
            const int row = seg * 8 + srow;
            GLL16(A + (size_t)(m0 + row) * K + k0 + schk * 8, As + seg * 512);
        }
        #pragma unroll
        for (int t = 0; t < 2; ++t) {    // B: 8 segments
            const int seg = wid * 2 + t;
            const int row = seg * 8 + srow;
            GLL16(W + (size_t)(n0 + row) * K + k0 + schk * 8, Bs + seg * 512);
        }
        __syncthreads();   // compiler drains vmcnt before barrier

        #pragma unroll
        for (int hh = 0; hh < 2; ++hh) {
            bf16x8 af[4], bf[2];
            const int sw = ln & 7;       // row&7 for all fragment rows
            #pragma unroll
            for (int i = 0; i < 4; ++i) {
                const int row = wm * 64 + i * 16 + ln;
                af[i] = *(const bf16x8*)&As[row * 64 + (((hh * 4 + quad) ^ sw) * 8)];
            }
            #pragma unroll
            for (int j = 0; j < 2; ++j) {
                const int row = wn * 32 + j * 16 + ln;
                bf[j] = *(const bf16x8*)&Bs[row * 64 + (((hh * 4 + quad) ^ sw) * 8)];
            }
            #pragma unroll
            for (int i = 0; i < 4; ++i)
                #pragma unroll
                for (int j = 0; j < 2; ++j)
                    acc[i][j] = __builtin_amdgcn_mfma_f32_16x16x32_bf16(
                        af[i], bf[j], acc[i][j], 0, 0, 0);
        }
    }

    const bool side2 = (n0 >= Nsplit);   // block-uniform
    #pragma unroll
    for (int i = 0; i < 4; ++i) {
        #pragma unroll
        for (int j = 0; j < 2; ++j) {
            const int col = n0 + wn * 32 + j * 16 + ln;
            const float bv = (!side2 && bias) ? bias[col] : 0.f;
            #pragma unroll
            for (int reg = 0; reg < 4; ++reg) {
                const int row = m0 + wm * 64 + i * 16 + quad * 4 + reg;
                const float v = acc[i][j][reg] + bv;
                if (side2)
                    Cout2[(size_t)row * N2 + (col - Nsplit)] = f2bf(v);
                else if (BF16_OUT)
                    ((ushort*)Cout)[(size_t)row * Nsplit + col] = f2bf(v);
                else
                    ((float*)Cout)[(size_t)row * Nsplit + col] = v;
            }
        }
    }
}

// ---------------------------------------------------------------------------
// Flash causal MQA attention, bf16 MFMA, m=0 softmax, S^T formulation.
// Key trick: compute S^T = mfma(A=K, B=Q) so each lane holds 4 CONSECUTIVE
// keys (C rows) for one q-column -> P packs into ds_write_b64 (4 bf16) into
// Ps[q][kk], and PV A-frag reads stay contiguous b128 (2-way banks = free).
// Each wave owns 32 q-rows (2x16 subtiles) sharing one kf/vf read set per
// k-tile (halves K/V LDS read traffic). Block = 4 waves = 128-row q-tile;
// triangle pairing p in 0..7: tiles B=15-p (always) and A=p (kt<=2p+1),
// 34 compute-subtiles per block, uniform. K/V reg-prefetched.
// ---------------------------------------------------------------------------
__global__ __launch_bounds__(256, 1) void attn_mfma_kernel(
    const ushort* __restrict__ qb,
    const ushort* __restrict__ kvb,
    ushort* __restrict__ yb)
{
    __shared__ ushort Ks[64][72];      // [kk][d], natural; rows 2-way = free
    __shared__ ushort Vt[64][72];      // [d][kk], chunk ^= swizzle (round-3)
    __shared__ ushort Ps[8][16][72];   // [wid*2+sub][q][kk]

    const int bh = blockIdx.x;
    const int b = bh >> 4, h = bh & 15;
    const int p = blockIdx.y;          // 0..7
    const int qB0 = (15 - p) * 128;    // heavy tile (always active)
    const int qA0 = p * 128;           // light tile (active kt <= 2p+1)
    const int tid = threadIdx.x;
    const int wid = tid >> 6;
    const int lane = tid & 63;
    const int ln = lane & 15;
    const int quad = lane >> 4;

    // Q fragments, B-operand layout: Q[q=ln][d = half*32 + quad*8 + j]
    const ushort* qstrip = qb + (size_t)b * T_N * C_N + (size_t)h * T_N * HS_N;
    const int qbase[2] = {qB0, qA0};
    bf16x8 qf[2][2][2];
    #pragma unroll
    for (int t = 0; t < 2; ++t)
        #pragma unroll
        for (int s = 0; s < 2; ++s) {
            const size_t r = (size_t)(qbase[t] + wid * 32 + s * 16 + ln) * HS_N;
            qf[t][s][0] = *(const bf16x8*)(qstrip + r + quad * 8);
            qf[t][s][1] = *(const bf16x8*)(qstrip + r + 32 + quad * 8);
        }

    f32x4 o[2][2][4];
    float l_i[2][2] = {{0.f, 0.f}, {0.f, 0.f}};
    #pragma unroll
    for (int t = 0; t < 2; ++t)
        #pragma unroll
        for (int s = 0; s < 2; ++s)
            #pragma unroll
            for (int nt = 0; nt < 4; ++nt)
                o[t][s][nt] = (f32x4){0.f, 0.f, 0.f, 0.f};

    const ushort* kvbase = kvb + (size_t)b * T_N * 128;
    const int rs = tid >> 3;   // 0..31 staging row
    const int cs = tid & 7;    // 0..7 staging 16B chunk

    int4 kc0, kc1, vc0, vc1;
    {   // prologue: k-tile 0
        const ushort* g0 = kvbase + (size_t)rs * 128 + cs * 8;
        kc0 = *(const int4*)g0;
        kc1 = *(const int4*)(g0 + 32 * 128);
        vc0 = *(const int4*)(g0 + 64);
        vc1 = *(const int4*)(g0 + 32 * 128 + 64);
    }

    bf16x8 kf[4][2], vf[4][2];

    // one 64-key tile for one 32-row q-subtile pair (tile t)
    auto tile_compute = [&](int t, int qt0, int k0) {
        #pragma unroll
        for (int s = 0; s < 2; ++s) {
            const int qg = qt0 + wid * 32 + s * 16 + ln;   // this lane's q-col
            f32x4 sc[4];
            #pragma unroll
            for (int nt = 0; nt < 4; ++nt) {
                sc[nt] = (f32x4){0.f, 0.f, 0.f, 0.f};
                sc[nt] = __builtin_amdgcn_mfma_f32_16x16x32_bf16(
                    kf[nt][0], qf[t][s][0], sc[nt], 0, 0, 0);
                sc[nt] = __builtin_amdgcn_mfma_f32_16x16x32_bf16(
                    kf[nt][1], qf[t][s][1], sc[nt], 0, 0, 0);
            }
            const bool dg = (k0 + 63 > qt0 + wid * 32 + s * 16);
            const int plane = wid * 2 + s;
            #pragma unroll
            for (int nt = 0; nt < 4; ++nt) {
                ushort pk[4];
                #pragma unroll
                for (int reg = 0; reg < 4; ++reg) {
                    const int key = k0 + nt * 16 + quad * 4 + reg;
                    float sv = sc[nt][reg];
                    if (dg && key > qg) sv = -1e30f;
                    const float pe = __builtin_amdgcn_exp2f(sv);
                    l_i[t][s] += pe;
                    pk[reg] = f2bf(pe);
                }
                *(uint2*)&Ps[plane][ln][nt * 16 + quad * 4] = *(uint2*)pk;
            }
            #pragma unroll
            for (int ks2 = 0; ks2 < 2; ++ks2) {
                const bf16x8 pf =
                    *(const bf16x8*)&Ps[plane][ln][ks2 * 32 + quad * 8];
                #pragma unroll
                for (int nt = 0; nt < 4; ++nt)
                    o[t][s][nt] = __builtin_amdgcn_mfma_f32_16x16x32_bf16(
                        pf, vf[nt][ks2], o[t][s][nt], 0, 0, 0);
            }
        }
    };

    const int nkt = 2 * (16 - p);
    for (int kt = 0; kt < nkt; ++kt) {
        const int k0 = kt * 64;
        __syncthreads();   // prior iteration's LDS reads complete
        *(int4*)&Ks[rs][cs * 8] = kc0;
        *(int4*)&Ks[rs + 32][cs * 8] = kc1;
        {
            const ushort* p0 = (const ushort*)&vc0;
            const ushort* p1 = (const ushort*)&vc1;
            const int pc0 = ((rs >> 3) ^ cs) * 8 + (rs & 7);
            const int pc1 = (((rs + 32) >> 3) ^ cs) * 8 + (rs & 7);
            #pragma unroll
            for (int i = 0; i < 8; ++i) {
                Vt[cs * 8 + i][pc0] = p0[i];
                Vt[cs * 8 + i][pc1] = p1[i];
            }
        }
        __syncthreads();
        if (kt + 1 < nkt) {   // prefetch next k-tile into regs
            const ushort* g0 = kvbase + (size_t)(k0 + 64 + rs) * 128 + cs * 8;
            kc0 = *(const int4*)g0;
            kc1 = *(const int4*)(g0 + 32 * 128);
            vc0 = *(const int4*)(g0 + 64);
            vc1 = *(const int4*)(g0 + 32 * 128 + 64);
        }
        // shared K/V fragments for this k-tile (read once, used by all subs)
        #pragma unroll
        for (int nt = 0; nt < 4; ++nt) {
            kf[nt][0] = *(const bf16x8*)&Ks[nt * 16 + ln][quad * 8];
            kf[nt][1] = *(const bf16x8*)&Ks[nt * 16 + ln][32 + quad * 8];
            #pragma unroll
            for (int ks2 = 0; ks2 < 2; ++ks2) {
                const int vsw = (2 * nt + (ln >> 3)) & 7;
                vf[nt][ks2] =
                    *(const bf16x8*)&Vt[nt * 16 + ln][((quad + 4 * ks2) ^ vsw) * 8];
            }
        }
        tile_compute(0, qB0, k0);
        if (kt <= 2 * p + 1)
            tile_compute(1, qA0, k0);
    }

    // epilogue: l lives per-lane at q=ln; reduce across quads, broadcast to
    // the C-layout row owners, write y = o / l
    #pragma unroll
    for (int t = 0; t < 2; ++t) {
        #pragma unroll
        for (int s = 0; s < 2; ++s) {
            float l = l_i[t][s];
            l += __shfl_xor(l, 16);
            l += __shfl_xor(l, 32);   // all lanes: full l for q = ln
            #pragma unroll
            for (int reg = 0; reg < 4; ++reg) {
                const float inv = 1.0f / __shfl(l, quad * 4 + reg);
                const int qg = qbase[t] + wid * 32 + s * 16 + quad * 4 + reg;
                ushort* yrow = yb + (size_t)b * T_N * C_N + (size_t)qg * C_N
                               + h * HS_N;
                #pragma unroll
                for (int nt = 0; nt < 4; ++nt)
                    yrow[nt * 16 + ln] = f2bf(o[t][s][nt][reg] * inv);
            }
        }
    }
}

// ---------------------------------------------------------------------------
extern "C" void kernel_launch(void* const* d_in, const int* in_sizes, int n_in,
                              void* d_out, int out_size, void* d_ws, size_t ws_size,
                              hipStream_t stream) {
    const float* x  = (const float*)d_in[0];
    const float* Wk = (const float*)d_in[1];
    const float* Wv = (const float*)d_in[2];
    const float* Wq = (const float*)d_in[3];
    const float* Wp = (const float*)d_in[4];
    const float* bp = (const float*)d_in[5];
    float* out = (float*)d_out;

    ushort* xb   = (ushort*)d_ws;                     // [4096][1024]
    ushort* qb   = xb   + (size_t)M_N * C_N;          // [4096][1024]
    ushort* yb   = qb   + (size_t)M_N * C_N;          // [4096][1024]
    ushort* kvb  = yb   + (size_t)M_N * C_N;          // [4096][128]
    ushort* Wqb  = kvb  + (size_t)M_N * 128;          // [1024][1024] (scaled)
    ushort* Wkvb = Wqb  + (size_t)C_N * C_N;          // [128][1024], after Wq
    ushort* Wpb  = Wkvb + (size_t)128 * C_N;          // [1024][1024]

    cvt_all_kernel<<<1024, 256, 0, stream>>>(x, Wq, Wp, Wk, Wv,
                                             xb, Wqb, Wpb, Wkvb);

    // fused q + kv projection: W' = [Wq(scaled); Wk; Wv] (1152 rows)
    gemm_bf16_mfma<true><<<dim3(M_N / 128, (C_N + 128) / 64), 256, 0, stream>>>(
        xb, Wqb, nullptr, qb, kvb, C_N, 128, C_N);

    // attention -> yb bf16 [4096][1024]; 128-row tile pairing (32 bh x 8)
    attn_mfma_kernel<<<dim3(B_N * H_N, 8), 256, 0, stream>>>(qb, kvb, yb);

    // out = y @ Wp^T + bp -> fp32
    gemm_bf16_mfma<false><<<dim3(M_N / 128, C_N / 64), 256, 0, stream>>>(
        yb, Wpb, bp, out, nullptr, C_N, 0, C_N);
}

// Round 6
// 154.329 us; speedup vs baseline: 1.0963x; 1.0963x over previous
//
#include <hip/hip_runtime.h>
#include <cstddef>
#include <cstdint>

// Problem constants: B=2, T=2048, C=1024, H=16, hs=64
#define B_N 2
#define T_N 2048
#define C_N 1024
#define H_N 16
#define HS_N 64
#define M_N (B_N * T_N)   // 4096

typedef __attribute__((ext_vector_type(8))) short bf16x8;   // 8 bf16 = 4 VGPRs
typedef __attribute__((ext_vector_type(4))) float f32x4;

// 0.125 (hs^-0.5) * log2(e): folded into Wq so attention uses exp2 directly
#define QSCALE 0.18033688011112042f

__device__ __forceinline__ ushort f2bf(float f) {
    union { float f; uint32_t u; } v; v.f = f;
    uint32_t r = v.u + 0x7fffu + ((v.u >> 16) & 1u);   // round-nearest-even
    return (ushort)(r >> 16);
}

// async global->LDS, 16B per lane; lds base must be wave-uniform
#define GLL16(g, l)                                                         \
    __builtin_amdgcn_global_load_lds(                                       \
        (const __attribute__((address_space(1))) unsigned int*)(g),         \
        (__attribute__((address_space(3))) unsigned int*)(l), 16, 0, 0)

// ---------------------------------------------------------------------------
// Fused fp32->bf16 convert: x | Wq(*QSCALE) | Wp | Wk | Wv (one launch).
// ---------------------------------------------------------------------------
__global__ void cvt_all_kernel(const float* __restrict__ x,
                               const float* __restrict__ Wq,
                               const float* __restrict__ Wp,
                               const float* __restrict__ Wk,
                               const float* __restrict__ Wv,
                               ushort* __restrict__ xb,
                               ushort* __restrict__ Wqb,
                               ushort* __restrict__ Wpb,
                               ushort* __restrict__ Wkvb) {
    const int S0 = M_N * C_N / 4;
    const int S1 = S0 + C_N * C_N / 4;
    const int S2 = S1 + C_N * C_N / 4;
    const int S3 = S2 + HS_N * C_N / 4;
    const int S4 = S3 + HS_N * C_N / 4;
    const int stride = gridDim.x * blockDim.x;
    for (int i = blockIdx.x * blockDim.x + threadIdx.x; i < S4; i += stride) {
        const float* src; ushort* dst; int j; float sc = 1.f;
        if (i < S0)      { src = x;  dst = xb;   j = i; }
        else if (i < S1) { src = Wq; dst = Wqb;  j = i - S0; sc = QSCALE; }
        else if (i < S2) { src = Wp; dst = Wpb;  j = i - S1; }
        else if (i < S3) { src = Wk; dst = Wkvb; j = i - S2; }
        else             { src = Wv; dst = Wkvb + HS_N * C_N; j = i - S3; }
        const float4 f = ((const float4*)src)[j];
        ushort4 o;
        o.x = f2bf(f.x * sc); o.y = f2bf(f.y * sc);
        o.z = f2bf(f.z * sc); o.w = f2bf(f.w * sc);
        ((ushort4*)dst)[j] = o;
    }
}

// ---------------------------------------------------------------------------
// bf16 MFMA GEMM, BM=BN=BK=64, 256 threads (4 waves 2x2, 32x32 each).
// Grid 4-4.5 blocks/CU -> GLL16 vmcnt drains + VALU latency overlap across
// resident blocks (round-5's 128x64 ran 2.25/CU with a 3-round tail).
// LDS unpadded, chunk XOR-swizzled by (row&7) (round-5-verified).
// MODE 0: fp32 out + bias.  MODE 1: bf16 out for n0<1024; n-tile 16 -> K
// natural [4096][64]; n-tile 17 -> V TRANSPOSED vbt[b][d][t] (packed ushort4,
// 4 C-regs = 4 consecutive t) so attention can stage Vt with plain b128.
// ---------------------------------------------------------------------------
template <int MODE>
__global__ __launch_bounds__(256) void gemm64(
    const ushort* __restrict__ A,   // [M][K] bf16
    const ushort* __restrict__ W,   // [Ntot][K] bf16
    const float* __restrict__ bias, // MODE 0 only
    void* __restrict__ Cout,        // [M][1024] fp32 (MODE 0) / bf16 (MODE 1)
    ushort* __restrict__ kb,        // MODE 1: [4096][64]
    ushort* __restrict__ vbt,       // MODE 1: [2][64][2048]
    int K)
{
    __shared__ ushort As[64 * 64];
    __shared__ ushort Bs[64 * 64];
    const int m0 = blockIdx.x * 64;
    const int n0 = blockIdx.y * 64;
    const int tid = threadIdx.x;
    const int wid = tid >> 6;
    const int lane = tid & 63;
    const int ln = lane & 15;
    const int quad = lane >> 4;
    const int wm = wid >> 1, wn = wid & 1;

    f32x4 acc[2][2];
    #pragma unroll
    for (int i = 0; i < 2; ++i)
        #pragma unroll
        for (int j = 0; j < 2; ++j)
            acc[i][j] = (f32x4){0.f, 0.f, 0.f, 0.f};

    const int srow = lane >> 3;          // 0..7 row within 8-row segment
    const int schk = (lane & 7) ^ srow;  // fetched chunk (row&7 == srow)

    for (int k0 = 0; k0 < K; k0 += 64) {
        __syncthreads();   // prior iteration's LDS reads complete
        #pragma unroll
        for (int t = 0; t < 2; ++t) {    // A: 8 segments of 8 rows
            const int seg = wid * 2 + t;
            GLL16(A + (size_t)(m0 + seg * 8 + srow) * K + k0 + schk * 8,
                  As + seg * 512);
        }
        #pragma unroll
        for (int t = 0; t < 2; ++t) {    // B: 8 segments
            const int seg = wid * 2 + t;
            GLL16(W + (size_t)(n0 + seg * 8 + srow) * K + k0 + schk * 8,
                  Bs + seg * 512);
        }
        __syncthreads();   // drains vmcnt (GLL16 counted there)

        #pragma unroll
        for (int hh = 0; hh < 2; ++hh) {
            bf16x8 af[2], bf[2];
            const int sw = ln & 7;
            #pragma unroll
            for (int i = 0; i < 2; ++i) {
                const int row = wm * 32 + i * 16 + ln;
                af[i] = *(const bf16x8*)&As[row * 64 + (((hh * 4 + quad) ^ sw) * 8)];
            }
            #pragma unroll
            for (int j = 0; j < 2; ++j) {
                const int row = wn * 32 + j * 16 + ln;
                bf[j] = *(const bf16x8*)&Bs[row * 64 + (((hh * 4 + quad) ^ sw) * 8)];
            }
            #pragma unroll
            for (int i = 0; i < 2; ++i)
                #pragma unroll
                for (int j = 0; j < 2; ++j)
                    acc[i][j] = __builtin_amdgcn_mfma_f32_16x16x32_bf16(
                        af[i], bf[j], acc[i][j], 0, 0, 0);
        }
    }

    if (MODE == 1 && n0 >= C_N) {
        const int c2base = n0 - C_N;                 // 0 (K-block) or 64 (V)
        const bool isV = (c2base >= 64);
        #pragma unroll
        for (int i = 0; i < 2; ++i) {
            const int row0 = m0 + wm * 32 + i * 16 + quad * 4;
            #pragma unroll
            for (int j = 0; j < 2; ++j) {
                const int c2 = c2base + wn * 32 + j * 16 + ln;
                if (isV) {
                    // vbt[b][d][t], 4 regs = 4 consecutive t
                    const int d = c2 - 64;
                    const int b = row0 >> 11;
                    const int t0 = row0 & 2047;
                    ushort4 pk;
                    pk.x = f2bf(acc[i][j][0]); pk.y = f2bf(acc[i][j][1]);
                    pk.z = f2bf(acc[i][j][2]); pk.w = f2bf(acc[i][j][3]);
                    *(ushort4*)&vbt[((size_t)b * 64 + d) * T_N + t0] = pk;
                } else {
                    #pragma unroll
                    for (int reg = 0; reg < 4; ++reg)
                        kb[(size_t)(row0 + reg) * 64 + c2] = f2bf(acc[i][j][reg]);
                }
            }
        }
        return;
    }

    #pragma unroll
    for (int i = 0; i < 2; ++i) {
        #pragma unroll
        for (int j = 0; j < 2; ++j) {
            const int col = n0 + wn * 32 + j * 16 + ln;
            const float bv = (MODE == 0) ? bias[col] : 0.f;
            #pragma unroll
            for (int reg = 0; reg < 4; ++reg) {
                const int row = m0 + wm * 32 + i * 16 + quad * 4 + reg;
                const float v = acc[i][j][reg] + bv;
                if (MODE == 0)
                    ((float*)Cout)[(size_t)row * C_N + col] = v;
                else
                    ((ushort*)Cout)[(size_t)row * C_N + col] = f2bf(v);
            }
        }
    }
}

// ---------------------------------------------------------------------------
// Flash causal MQA attention, bf16 MFMA, m=0 softmax, S^T formulation
// (round-5-verified math), re-gridded for occupancy:
// Grid 32bh x 16 pairs = 512 blocks (2/CU, 8 waves/CU = 2/SIMD).
// Block owns 64-row tiles A=p (light) and B=31-p (heavy); each wave takes
// 16 q of B (every kt) + 16 q of A (kt <= p): 33 subtile-computes uniform.
// kf/vf fragments read once per kt, shared by both subtiles.
// V comes pre-transposed from global (vbt) -> Vt staged with 2 b128 writes
// per thread (round-5's 16 scalar b16 transpose eliminated).
// ---------------------------------------------------------------------------
__global__ __launch_bounds__(256, 2) void attn_mfma_kernel(
    const ushort* __restrict__ qb,
    const ushort* __restrict__ kb,    // [4096][64]
    const ushort* __restrict__ vbt,   // [2][64][2048]
    ushort* __restrict__ yb)
{
    __shared__ ushort Ks[64][72];      // [kk][d]
    __shared__ ushort Vt[64][72];      // [d][kk]
    __shared__ ushort Ps[4][16][72];   // per-wave [q][kk]

    const int bh = blockIdx.x;
    const int b = bh >> 4, h = bh & 15;
    const int p = blockIdx.y;          // 0..15
    const int qA0 = p * 64;            // light tile (active kt <= p)
    const int qB0 = (31 - p) * 64;     // heavy tile (always active)
    const int tid = threadIdx.x;
    const int wid = tid >> 6;
    const int lane = tid & 63;
    const int ln = lane & 15;
    const int quad = lane >> 4;

    // Q fragments, B-operand layout: Q[q=ln][d = half*32 + quad*8 + j]
    const ushort* qstrip = qb + (size_t)b * T_N * C_N + (size_t)h * T_N * HS_N;
    const size_t rB = (size_t)(qB0 + wid * 16 + ln) * HS_N;
    const size_t rA = (size_t)(qA0 + wid * 16 + ln) * HS_N;
    bf16x8 qfB[2], qfA[2];
    qfB[0] = *(const bf16x8*)(qstrip + rB + quad * 8);
    qfB[1] = *(const bf16x8*)(qstrip + rB + 32 + quad * 8);
    qfA[0] = *(const bf16x8*)(qstrip + rA + quad * 8);
    qfA[1] = *(const bf16x8*)(qstrip + rA + 32 + quad * 8);

    f32x4 oB[4], oA[4];
    float lB = 0.f, lA = 0.f;
    #pragma unroll
    for (int nt = 0; nt < 4; ++nt) {
        oB[nt] = (f32x4){0.f, 0.f, 0.f, 0.f};
        oA[nt] = (f32x4){0.f, 0.f, 0.f, 0.f};
    }

    const ushort* kbase = kb + (size_t)b * T_N * HS_N;
    const ushort* vtbase = vbt + (size_t)b * HS_N * T_N;
    const int rs = tid >> 3;   // 0..31 staging row
    const int cs = tid & 7;    // 0..7 staging 16B chunk

    int4 kc0, kc1, vc0, vc1;
    {   // prologue: k-tile 0
        kc0 = *(const int4*)(kbase + (size_t)rs * HS_N + cs * 8);
        kc1 = *(const int4*)(kbase + (size_t)(rs + 32) * HS_N + cs * 8);
        vc0 = *(const int4*)(vtbase + (size_t)rs * T_N + cs * 8);
        vc1 = *(const int4*)(vtbase + (size_t)(rs + 32) * T_N + cs * 8);
    }

    bf16x8 kf[4][2], vf[4][2];

    // one 64-key tile for one 16-q subtile
    auto tile_compute = [&](const bf16x8* qf, f32x4* o, float& l,
                            int qt0, int k0) {
        const int qs0 = qt0 + wid * 16;
        const int qg = qs0 + ln;          // this lane's q-column
        f32x4 sc[4];
        #pragma unroll
        for (int nt = 0; nt < 4; ++nt) {
            sc[nt] = (f32x4){0.f, 0.f, 0.f, 0.f};
            sc[nt] = __builtin_amdgcn_mfma_f32_16x16x32_bf16(
                kf[nt][0], qf[0], sc[nt], 0, 0, 0);
            sc[nt] = __builtin_amdgcn_mfma_f32_16x16x32_bf16(
                kf[nt][1], qf[1], sc[nt], 0, 0, 0);
        }
        const bool dg = (k0 + 63 > qs0);
        #pragma unroll
        for (int nt = 0; nt < 4; ++nt) {
            ushort pk[4];
            #pragma unroll
            for (int reg = 0; reg < 4; ++reg) {
                const int key = k0 + nt * 16 + quad * 4 + reg;
                float sv = sc[nt][reg];
                if (dg && key > qg) sv = -1e30f;
                const float pe = __builtin_amdgcn_exp2f(sv);
                l += pe;
                pk[reg] = f2bf(pe);
            }
            *(uint2*)&Ps[wid][ln][nt * 16 + quad * 4] = *(const uint2*)pk;
        }
        #pragma unroll
        for (int ks2 = 0; ks2 < 2; ++ks2) {
            const bf16x8 pf = *(const bf16x8*)&Ps[wid][ln][ks2 * 32 + quad * 8];
            #pragma unroll
            for (int nt = 0; nt < 4; ++nt)
                o[nt] = __builtin_amdgcn_mfma_f32_16x16x32_bf16(
                    pf, vf[nt][ks2], o[nt], 0, 0, 0);
        }
    };

    const int nkt = 32 - p;
    for (int kt = 0; kt < nkt; ++kt) {
        const int k0 = kt * 64;
        __syncthreads();   // prior iteration's LDS reads complete
        *(int4*)&Ks[rs][cs * 8] = kc0;
        *(int4*)&Ks[rs + 32][cs * 8] = kc1;
        *(int4*)&Vt[rs][cs * 8] = vc0;
        *(int4*)&Vt[rs + 32][cs * 8] = vc1;
        __syncthreads();
        if (kt + 1 < nkt) {   // prefetch next k-tile into regs
            const int kn = k0 + 64;
            kc0 = *(const int4*)(kbase + (size_t)(kn + rs) * HS_N + cs * 8);
            kc1 = *(const int4*)(kbase + (size_t)(kn + rs + 32) * HS_N + cs * 8);
            vc0 = *(const int4*)(vtbase + (size_t)rs * T_N + kn + cs * 8);
            vc1 = *(const int4*)(vtbase + (size_t)(rs + 32) * T_N + kn + cs * 8);
        }
        // shared K/V fragments for this k-tile (read once, both subtiles)
        #pragma unroll
        for (int nt = 0; nt < 4; ++nt) {
            kf[nt][0] = *(const bf16x8*)&Ks[nt * 16 + ln][quad * 8];
            kf[nt][1] = *(const bf16x8*)&Ks[nt * 16 + ln][32 + quad * 8];
            vf[nt][0] = *(const bf16x8*)&Vt[nt * 16 + ln][quad * 8];
            vf[nt][1] = *(const bf16x8*)&Vt[nt * 16 + ln][32 + quad * 8];
        }
        tile_compute(qfB, oB, lB, qB0, k0);
        if (kt <= p)
            tile_compute(qfA, oA, lA, qA0, k0);
    }

    // epilogue: l lives per-lane at q=ln; reduce across quads, broadcast to
    // the C-layout row owners, write y = o / l
    #pragma unroll
    for (int t = 0; t < 2; ++t) {
        float l = t ? lA : lB;
        const f32x4* o = t ? oA : oB;
        const int qt0 = t ? qA0 : qB0;
        l += __shfl_xor(l, 16);
        l += __shfl_xor(l, 32);   // all lanes hold full l for q = ln
        #pragma unroll
        for (int reg = 0; reg < 4; ++reg) {
            const float inv = 1.0f / __shfl(l, quad * 4 + reg);
            const int qg = qt0 + wid * 16 + quad * 4 + reg;
            ushort* yrow = yb + (size_t)b * T_N * C_N + (size_t)qg * C_N
                           + h * HS_N;
            #pragma unroll
            for (int nt = 0; nt < 4; ++nt)
                yrow[nt * 16 + ln] = f2bf(o[nt][reg] * inv);
        }
    }
}

// ---------------------------------------------------------------------------
extern "C" void kernel_launch(void* const* d_in, const int* in_sizes, int n_in,
                              void* d_out, int out_size, void* d_ws, size_t ws_size,
                              hipStream_t stream) {
    const float* x  = (const float*)d_in[0];
    const float* Wk = (const float*)d_in[1];
    const float* Wv = (const float*)d_in[2];
    const float* Wq = (const float*)d_in[3];
    const float* Wp = (const float*)d_in[4];
    const float* bp = (const float*)d_in[5];
    float* out = (float*)d_out;

    ushort* xb   = (ushort*)d_ws;                     // [4096][1024]
    ushort* qb   = xb   + (size_t)M_N * C_N;          // [4096][1024]
    ushort* yb   = qb   + (size_t)M_N * C_N;          // [4096][1024]
    ushort* kbw  = yb   + (size_t)M_N * C_N;          // [4096][64]
    ushort* vbt  = kbw  + (size_t)M_N * HS_N;         // [2][64][2048]
    ushort* Wqb  = vbt  + (size_t)B_N * HS_N * T_N;   // [1024][1024] (scaled)
    ushort* Wkvb = Wqb  + (size_t)C_N * C_N;          // [128][1024], after Wq
    ushort* Wpb  = Wkvb + (size_t)128 * C_N;          // [1024][1024]

    cvt_all_kernel<<<1024, 256, 0, stream>>>(x, Wq, Wp, Wk, Wv,
                                             xb, Wqb, Wpb, Wkvb);

    // fused q + k + v projection: W' = [Wq(scaled); Wk; Wv] (1152 rows)
    // n-tiles 0..15 -> qb, 16 -> kbw (natural), 17 -> vbt (transposed)
    gemm64<1><<<dim3(M_N / 64, (C_N + 128) / 64), 256, 0, stream>>>(
        xb, Wqb, nullptr, qb, kbw, vbt, C_N);

    // attention -> yb bf16 [4096][1024]; paired 64-row tiles (32bh x 16)
    attn_mfma_kernel<<<dim3(B_N * H_N, 16), 256, 0, stream>>>(qb, kbw, vbt, yb);

    // out = y @ Wp^T + bp -> fp32
    gemm64<0><<<dim3(M_N / 64, C_N / 64), 256, 0, stream>>>(
        yb, Wpb, bp, out, nullptr, nullptr, C_N);
}